// Round 1
// baseline (716.176 us; speedup 1.0000x reference)
//
#include <hip/hip_runtime.h>
#include <math.h>

#define N_NODESC 100000
#define N_EDGESC 1600000
#define IN_DIMC 256
#define HIDC 64
#define ALPHAC 0.1f
#define BIASC 1e-4f
#define EOSC 1e-10f

// ---------------------------------------------------------------------------
// detect: edges may arrive as int32 (JAX x64-off) or int64. If int64 (LE),
// every odd 32-bit word of small non-negative values is 0.
__global__ void detect_kernel(const int* __restrict__ edges, int* __restrict__ flag) {
    if (threadIdx.x == 0 && blockIdx.x == 0) {
        int z = 0;
        #pragma unroll
        for (int i = 0; i < 16; ++i) z |= edges[2 * i + 1];
        *flag = (z == 0) ? 1 : 0;  // 1 => int64 layout
    }
}

__device__ inline void load_edge(const int* __restrict__ edges, int e, int is64,
                                 int& src, int& dst) {
    if (is64) {
        src = edges[2 * e];
        dst = edges[2 * (N_EDGESC + e)];
    } else {
        src = edges[e];
        dst = edges[N_EDGESC + e];
    }
}

__device__ inline float wave_sum(float v) {
    #pragma unroll
    for (int off = 32; off > 0; off >>= 1) v += __shfl_down(v, off);
    return v;
}

// ---------------------------------------------------------------------------
// node kernel: q[n] = relu(feat[n] @ W_emb + b_emb) @ (W_edge[:64]+W_edge[64:])
// Also initializes the 4 degree arrays to 1+EOS (self-loop contribution).
// Block = 256 (4 waves); lane = hidden dim; 4 nodes per wave per tile.
// W_emb staged in LDS (64 KB) once per block -> 2 blocks/CU.
__global__ __launch_bounds__(256, 2) void node_kernel(
    const float* __restrict__ features,
    const float* __restrict__ W_emb,
    const float* __restrict__ b_emb,
    const float* __restrict__ W_edge,
    float* __restrict__ q,
    float* __restrict__ deg) {
    __shared__ float Wl[IN_DIMC * HIDC];  // 64 KB
    const int tid = threadIdx.x;
    {
        const float4* Wg = (const float4*)W_emb;
        float4* Ws = (float4*)Wl;
        #pragma unroll
        for (int i = 0; i < (IN_DIMC * HIDC / 4) / 256; ++i)
            Ws[tid + 256 * i] = Wg[tid + 256 * i];
    }
    const int lane = tid & 63;
    const int wave = tid >> 6;
    const float bj = b_emb[lane];
    const float wsum = W_edge[lane] + W_edge[HIDC + lane];
    __syncthreads();

    const int n_tiles = N_NODESC / 16;  // 6250, exact
    for (int tile = blockIdx.x; tile < n_tiles; tile += gridDim.x) {
        const int node0 = tile * 16 + wave * 4;
        const float* f0 = features + (size_t)node0 * IN_DIMC;
        float acc0 = bj, acc1 = bj, acc2 = bj, acc3 = bj;
        #pragma unroll 2
        for (int k = 0; k < IN_DIMC; k += 4) {
            const float w0 = Wl[(k + 0) * HIDC + lane];
            const float w1 = Wl[(k + 1) * HIDC + lane];
            const float w2 = Wl[(k + 2) * HIDC + lane];
            const float w3 = Wl[(k + 3) * HIDC + lane];
            const float4 fa = *(const float4*)(f0 + k);
            const float4 fb = *(const float4*)(f0 + IN_DIMC + k);
            const float4 fc = *(const float4*)(f0 + 2 * IN_DIMC + k);
            const float4 fd = *(const float4*)(f0 + 3 * IN_DIMC + k);
            acc0 = fmaf(fa.x, w0, acc0); acc0 = fmaf(fa.y, w1, acc0);
            acc0 = fmaf(fa.z, w2, acc0); acc0 = fmaf(fa.w, w3, acc0);
            acc1 = fmaf(fb.x, w0, acc1); acc1 = fmaf(fb.y, w1, acc1);
            acc1 = fmaf(fb.z, w2, acc1); acc1 = fmaf(fb.w, w3, acc1);
            acc2 = fmaf(fc.x, w0, acc2); acc2 = fmaf(fc.y, w1, acc2);
            acc2 = fmaf(fc.z, w2, acc2); acc2 = fmaf(fc.w, w3, acc2);
            acc3 = fmaf(fd.x, w0, acc3); acc3 = fmaf(fd.y, w1, acc3);
            acc3 = fmaf(fd.z, w2, acc3); acc3 = fmaf(fd.w, w3, acc3);
        }
        const float v0 = wave_sum(fmaxf(acc0, 0.f) * wsum);
        const float v1 = wave_sum(fmaxf(acc1, 0.f) * wsum);
        const float v2 = wave_sum(fmaxf(acc2, 0.f) * wsum);
        const float v3 = wave_sum(fmaxf(acc3, 0.f) * wsum);
        if (lane == 0) {
            q[node0 + 0] = v0; q[node0 + 1] = v1;
            q[node0 + 2] = v2; q[node0 + 3] = v3;
            const float ini = 1.0f + EOSC;
            #pragma unroll
            for (int m = 0; m < 4; ++m) {
                deg[node0 + m] = ini;
                deg[N_NODESC + node0 + m] = ini;
                deg[2 * N_NODESC + node0 + m] = ini;
                deg[3 * N_NODESC + node0 + m] = ini;
            }
        }
    }
}

// ---------------------------------------------------------------------------
// edge kernel: gumbel-sigmoid weights + degree accumulation (4 atomics/edge).
// out layout: [0,M) lp_norm | [M,2M) hp_norm | [2M,2M+E) wlp | [2M+E,2M+2E) whp
__global__ __launch_bounds__(256) void edge_kernel(
    const int* __restrict__ edges,
    const float* __restrict__ noise,
    const float* __restrict__ b_edge,
    const float* __restrict__ q,
    float* __restrict__ deg,
    float* __restrict__ out,
    const int* __restrict__ flag) {
    const int e = blockIdx.x * blockDim.x + threadIdx.x;
    if (e >= N_EDGESC) return;
    const int is64 = *flag;
    int src, dst;
    load_edge(edges, e, is64, src, dst);
    const float raw = 0.5f * (q[src] + q[dst]) + b_edge[0];
    const float u = noise[e];
    const float eps = (BIASC - (1.0f - BIASC)) * u + (1.0f - BIASC);
    const float gate = logf(eps) - log1pf(-eps);
    const float x = gate + raw;
    const float wlp = 1.0f / (1.0f + expf(-x));
    const float whp = 1.0f - wlp;
    const int M2 = 2 * (N_EDGESC + N_NODESC);
    out[M2 + e] = wlp;
    out[M2 + N_EDGESC + e] = whp;
    const float wl = wlp + EOSC;
    const float wh = whp + EOSC;
    atomicAdd(&deg[src], wl);                   // out-deg lp
    atomicAdd(&deg[N_NODESC + dst], wl);        // in-deg lp
    atomicAdd(&deg[2 * N_NODESC + src], wh);    // out-deg hp
    atomicAdd(&deg[3 * N_NODESC + dst], wh);    // in-deg hp
}

// ---------------------------------------------------------------------------
// final kernel: normalized weights for edges and self-loops.
__global__ __launch_bounds__(256) void final_kernel(
    const int* __restrict__ edges,
    const float* __restrict__ deg,
    float* __restrict__ out,
    const int* __restrict__ flag) {
    const int i = blockIdx.x * blockDim.x + threadIdx.x;
    const int M = N_EDGESC + N_NODESC;
    if (i >= M) return;
    if (i < N_EDGESC) {
        const int is64 = *flag;
        int src, dst;
        load_edge(edges, i, is64, src, dst);
        const float wlp = out[2 * M + i] + EOSC;
        const float whp = out[2 * M + N_EDGESC + i] + EOSC;
        out[i] = wlp * rsqrtf(deg[src] * deg[N_NODESC + dst]);
        out[M + i] = -ALPHAC * whp *
                     rsqrtf(deg[2 * N_NODESC + src] * deg[3 * N_NODESC + dst]);
    } else {
        const int n = i - N_EDGESC;
        out[i] = (1.0f + EOSC) * rsqrtf(deg[n] * deg[N_NODESC + n]);
        out[M + i] = 1.0f;
    }
}

// ---------------------------------------------------------------------------
extern "C" void kernel_launch(void* const* d_in, const int* in_sizes, int n_in,
                              void* d_out, int out_size, void* d_ws, size_t ws_size,
                              hipStream_t stream) {
    const float* features = (const float*)d_in[0];
    const int* edges      = (const int*)d_in[1];
    const float* noise    = (const float*)d_in[2];
    const float* W_emb    = (const float*)d_in[3];
    const float* b_emb    = (const float*)d_in[4];
    const float* W_edge   = (const float*)d_in[5];
    const float* b_edge   = (const float*)d_in[6];
    float* out = (float*)d_out;
    float* ws  = (float*)d_ws;

    float* q   = ws;                    // N floats
    float* deg = ws + N_NODESC;         // 4*N floats
    int* flag  = (int*)(ws + 5 * N_NODESC);

    detect_kernel<<<1, 64, 0, stream>>>(edges, flag);
    node_kernel<<<512, 256, 0, stream>>>(features, W_emb, b_emb, W_edge, q, deg);
    edge_kernel<<<(N_EDGESC + 255) / 256, 256, 0, stream>>>(edges, noise, b_edge,
                                                            q, deg, out, flag);
    final_kernel<<<(N_EDGESC + N_NODESC + 255) / 256, 256, 0, stream>>>(edges, deg,
                                                                        out, flag);
}

// Round 2
// 534.239 us; speedup vs baseline: 1.3406x; 1.3406x over previous
//
#include <hip/hip_runtime.h>
#include <math.h>

#define N_NODESC 100000
#define N_EDGESC 1600000
#define IN_DIMC 256
#define HIDC 64
#define ALPHAC 0.1f
#define BIASC 1e-4f
#define EOSC 1e-10f

#define FIXSCALE 16777216.0f      // 2^24
#define FIXINV   (1.0f / 16777216.0f)
#define SUMMASK  0xFFFFFFFFFFull  // low 40 bits
#define CNTONE   (1ull << 40)

// edges may arrive as int32 (JAX x64-off) or int64 little-endian.
__device__ inline void load_edge(const int* __restrict__ edges, int e, int is64,
                                 int& src, int& dst) {
    if (is64) {
        src = edges[2 * e];
        dst = edges[2 * (N_EDGESC + e)];
    } else {
        src = edges[e];
        dst = edges[N_EDGESC + e];
    }
}

__device__ inline float wave_sum(float v) {
    #pragma unroll
    for (int off = 32; off > 0; off >>= 1) v += __shfl_down(v, off);
    return v;
}

// ---------------------------------------------------------------------------
// node kernel: q[n] = relu(feat[n] @ W_emb + b_emb) @ (W_edge[:64]+W_edge[64:])
// block 0 / thread 0 also performs the int32-vs-int64 edge layout detection.
__global__ __launch_bounds__(256, 2) void node_kernel(
    const float* __restrict__ features,
    const float* __restrict__ W_emb,
    const float* __restrict__ b_emb,
    const float* __restrict__ W_edge,
    const int* __restrict__ edges,
    float* __restrict__ q,
    int* __restrict__ flag) {
    __shared__ float Wl[IN_DIMC * HIDC];  // 64 KB
    const int tid = threadIdx.x;
    if (blockIdx.x == 0 && tid == 0) {
        int z = 0;
        #pragma unroll
        for (int i = 0; i < 16; ++i) z |= edges[2 * i + 1];
        *flag = (z == 0) ? 1 : 0;  // 1 => int64 layout
    }
    {
        const float4* Wg = (const float4*)W_emb;
        float4* Ws = (float4*)Wl;
        #pragma unroll
        for (int i = 0; i < (IN_DIMC * HIDC / 4) / 256; ++i)
            Ws[tid + 256 * i] = Wg[tid + 256 * i];
    }
    const int lane = tid & 63;
    const int wave = tid >> 6;
    const float bj = b_emb[lane];
    const float wsum = W_edge[lane] + W_edge[HIDC + lane];
    __syncthreads();

    const int n_tiles = N_NODESC / 16;  // 6250, exact
    for (int tile = blockIdx.x; tile < n_tiles; tile += gridDim.x) {
        const int node0 = tile * 16 + wave * 4;
        const float* f0 = features + (size_t)node0 * IN_DIMC;
        float acc0 = bj, acc1 = bj, acc2 = bj, acc3 = bj;
        #pragma unroll 2
        for (int k = 0; k < IN_DIMC; k += 4) {
            const float w0 = Wl[(k + 0) * HIDC + lane];
            const float w1 = Wl[(k + 1) * HIDC + lane];
            const float w2 = Wl[(k + 2) * HIDC + lane];
            const float w3 = Wl[(k + 3) * HIDC + lane];
            const float4 fa = *(const float4*)(f0 + k);
            const float4 fb = *(const float4*)(f0 + IN_DIMC + k);
            const float4 fc = *(const float4*)(f0 + 2 * IN_DIMC + k);
            const float4 fd = *(const float4*)(f0 + 3 * IN_DIMC + k);
            acc0 = fmaf(fa.x, w0, acc0); acc0 = fmaf(fa.y, w1, acc0);
            acc0 = fmaf(fa.z, w2, acc0); acc0 = fmaf(fa.w, w3, acc0);
            acc1 = fmaf(fb.x, w0, acc1); acc1 = fmaf(fb.y, w1, acc1);
            acc1 = fmaf(fb.z, w2, acc1); acc1 = fmaf(fb.w, w3, acc1);
            acc2 = fmaf(fc.x, w0, acc2); acc2 = fmaf(fc.y, w1, acc2);
            acc2 = fmaf(fc.z, w2, acc2); acc2 = fmaf(fc.w, w3, acc2);
            acc3 = fmaf(fd.x, w0, acc3); acc3 = fmaf(fd.y, w1, acc3);
            acc3 = fmaf(fd.z, w2, acc3); acc3 = fmaf(fd.w, w3, acc3);
        }
        const float v0 = wave_sum(fmaxf(acc0, 0.f) * wsum);
        const float v1 = wave_sum(fmaxf(acc1, 0.f) * wsum);
        const float v2 = wave_sum(fmaxf(acc2, 0.f) * wsum);
        const float v3 = wave_sum(fmaxf(acc3, 0.f) * wsum);
        if (lane == 0) {
            q[node0 + 0] = v0; q[node0 + 1] = v1;
            q[node0 + 2] = v2; q[node0 + 3] = v3;
        }
    }
}

// ---------------------------------------------------------------------------
// edge kernel: gumbel-sigmoid weights + packed-u64 degree accumulation.
// One u64 atomic per endpoint: low 40 bits = fixed-point sum(wlp), bits 40+ = count.
__global__ __launch_bounds__(256) void edge_kernel(
    const int* __restrict__ edges,
    const float* __restrict__ noise,
    const float* __restrict__ b_edge,
    const float* __restrict__ q,
    unsigned long long* __restrict__ accS,
    unsigned long long* __restrict__ accD,
    float* __restrict__ out,
    const int* __restrict__ flag) {
    const int e = blockIdx.x * blockDim.x + threadIdx.x;
    if (e >= N_EDGESC) return;
    const int is64 = *flag;
    int src, dst;
    load_edge(edges, e, is64, src, dst);
    const float raw = 0.5f * (q[src] + q[dst]) + b_edge[0];
    const float u = noise[e];
    const float eps = (BIASC - (1.0f - BIASC)) * u + (1.0f - BIASC);
    const float gate = logf(eps) - log1pf(-eps);
    const float x = gate + raw;
    const float wlp = 1.0f / (1.0f + expf(-x));
    const int M2 = 2 * (N_EDGESC + N_NODESC);
    out[M2 + e] = wlp;
    out[M2 + N_EDGESC + e] = 1.0f - wlp;
    const unsigned long long t =
        (unsigned long long)(wlp * FIXSCALE + 0.5f) + CNTONE;
    atomicAdd(&accS[src], t);
    atomicAdd(&accD[dst], t);
}

// ---------------------------------------------------------------------------
// prep kernel: decode accumulators -> per-node rsqrt vector
// {r_lp_out, r_lp_in, r_hp_out, r_hp_in}
__global__ __launch_bounds__(256) void prep_kernel(
    const unsigned long long* __restrict__ accS,
    const unsigned long long* __restrict__ accD,
    float4* __restrict__ rnode) {
    const int n = blockIdx.x * blockDim.x + threadIdx.x;
    if (n >= N_NODESC) return;
    const unsigned long long a = accS[n];
    const unsigned long long b = accD[n];
    const float sumS = (float)(a & SUMMASK) * FIXINV;
    const float cntS = (float)(a >> 40);
    const float sumD = (float)(b & SUMMASK) * FIXINV;
    const float cntD = (float)(b >> 40);
    float4 r;
    r.x = rsqrtf(1.0f + sumS);          // deg_lp_out
    r.y = rsqrtf(1.0f + sumD);          // deg_lp_in
    r.z = rsqrtf(1.0f + cntS - sumS);   // deg_hp_out
    r.w = rsqrtf(1.0f + cntD - sumD);   // deg_hp_in
    rnode[n] = r;
}

// ---------------------------------------------------------------------------
// final kernel: normalized weights for edges and self-loops.
__global__ __launch_bounds__(256) void final_kernel(
    const int* __restrict__ edges,
    const float4* __restrict__ rnode,
    float* __restrict__ out,
    const int* __restrict__ flag) {
    const int i = blockIdx.x * blockDim.x + threadIdx.x;
    const int M = N_EDGESC + N_NODESC;
    if (i >= M) return;
    if (i < N_EDGESC) {
        const int is64 = *flag;
        int src, dst;
        load_edge(edges, i, is64, src, dst);
        const float wlp = out[2 * M + i] + EOSC;
        const float whp = out[2 * M + N_EDGESC + i] + EOSC;
        const float4 rs = rnode[src];
        const float4 rd = rnode[dst];
        out[i] = wlp * rs.x * rd.y;
        out[M + i] = -ALPHAC * whp * rs.z * rd.w;
    } else {
        const int n = i - N_EDGESC;
        const float4 r = rnode[n];
        out[i] = (1.0f + EOSC) * r.x * r.y;
        out[M + i] = 1.0f;
    }
}

// ---------------------------------------------------------------------------
extern "C" void kernel_launch(void* const* d_in, const int* in_sizes, int n_in,
                              void* d_out, int out_size, void* d_ws, size_t ws_size,
                              hipStream_t stream) {
    const float* features = (const float*)d_in[0];
    const int* edges      = (const int*)d_in[1];
    const float* noise    = (const float*)d_in[2];
    const float* W_emb    = (const float*)d_in[3];
    const float* b_emb    = (const float*)d_in[4];
    const float* W_edge   = (const float*)d_in[5];
    const float* b_edge   = (const float*)d_in[6];
    float* out = (float*)d_out;
    char* ws = (char*)d_ws;

    // ws layout (bytes):
    //   [0, 400000)            q        : N f32
    //   [400000, 2000000)      accS/accD: 2*N u64
    //   [2000000, 3600000)     rnode    : N float4
    //   [3600000, 3600004)     flag
    float* q = (float*)ws;
    unsigned long long* accS = (unsigned long long*)(ws + 400000);
    unsigned long long* accD = accS + N_NODESC;
    float4* rnode = (float4*)(ws + 2000000);
    int* flag = (int*)(ws + 3600000);

    hipMemsetAsync(accS, 0, 2 * N_NODESC * sizeof(unsigned long long), stream);
    node_kernel<<<512, 256, 0, stream>>>(features, W_emb, b_emb, W_edge, edges,
                                         q, flag);
    edge_kernel<<<(N_EDGESC + 255) / 256, 256, 0, stream>>>(edges, noise, b_edge,
                                                            q, accS, accD, out, flag);
    prep_kernel<<<(N_NODESC + 255) / 256, 256, 0, stream>>>(accS, accD, rnode);
    final_kernel<<<(N_EDGESC + N_NODESC + 255) / 256, 256, 0, stream>>>(edges, rnode,
                                                                        out, flag);
}

// Round 3
// 346.085 us; speedup vs baseline: 2.0694x; 1.5437x over previous
//
#include <hip/hip_runtime.h>
#include <hip/hip_bf16.h>
#include <math.h>

#define N_NODESC 100000
#define N_EDGESC 1600000
#define IN_DIMC 256
#define HIDC 64
#define ALPHAC 0.1f
#define BIASC 1e-4f
#define EOSC 1e-10f

#define FIXSCALE 16777216.0f      // 2^24
#define FIXINV   (1.0f / 16777216.0f)
#define SUMMASK  0xFFFFFFFFFFull  // low 40 bits
#define CNTONE   (1ull << 40)

typedef __attribute__((ext_vector_type(8))) short short8;
typedef __attribute__((ext_vector_type(4))) float f32x4;

#define WT_STRIDE 264  // bf16 per j-row: 256 + 8 pad (528 B, 16B-aligned)

// edges may arrive as int32 (JAX x64-off) or int64 little-endian.
__device__ inline void load_edge(const int* __restrict__ edges, int e, int is64,
                                 int& src, int& dst) {
    if (is64) {
        const int2 a = ((const int2*)edges)[e];
        const int2 b = ((const int2*)edges)[N_EDGESC + e];
        src = a.x; dst = b.x;
    } else {
        src = edges[e];
        dst = edges[N_EDGESC + e];
    }
}

__device__ inline short pkbf(float x) {
    union { __hip_bfloat16 b; short s; } u;
    u.b = __float2bfloat16(x);
    return u.s;
}

// ---------------------------------------------------------------------------
// node kernel (MFMA): q[n] = relu(feat[n] @ W + b) @ (We[:64]+We[64:])
// Block = 256 (4 waves). Each wave: 16 nodes x 64 hidden via 4 n-tiles of
// 16x16x32 bf16 MFMA, K-loop of 8. A read straight from global (coalesced,
// read-once); B = W_emb as bf16 in LDS, transposed, padded.
__global__ __launch_bounds__(256, 4) void node_kernel(
    const float* __restrict__ features,
    const float* __restrict__ W_emb,
    const float* __restrict__ b_emb,
    const float* __restrict__ W_edge,
    const int* __restrict__ edges,
    float* __restrict__ q,
    int* __restrict__ flag) {
    __shared__ __align__(16) short Wt[HIDC * WT_STRIDE];  // ~33.8 KB
    const int tid = threadIdx.x;
    if (blockIdx.x == 0 && tid == 0) {
        int z = 0;
        #pragma unroll
        for (int i = 0; i < 16; ++i) z |= edges[2 * i + 1];
        *flag = (z == 0) ? 1 : 0;  // 1 => int64 layout
    }
    // stage W_emb [k][j] fp32 -> Wt[j][k] bf16 (transposed, padded)
    {
        const float4* Wg = (const float4*)W_emb;
        #pragma unroll
        for (int i = 0; i < 16; ++i) {
            const int f4 = tid + 256 * i;
            const float4 g = Wg[f4];
            const int flat = 4 * f4;
            const int k = flat >> 6;        // input dim
            const int j0 = flat & 63;       // hidden dim
            Wt[(j0 + 0) * WT_STRIDE + k] = pkbf(g.x);
            Wt[(j0 + 1) * WT_STRIDE + k] = pkbf(g.y);
            Wt[(j0 + 2) * WT_STRIDE + k] = pkbf(g.z);
            Wt[(j0 + 3) * WT_STRIDE + k] = pkbf(g.w);
        }
    }
    const int lane = tid & 63;
    const int wave = tid >> 6;
    const int quad = lane >> 4;   // 0..3
    const int m = lane & 15;      // node-local row; also B's n (hidden j mod 16)
    // per-lane constants: bias & wsum for hidden dims j = m + 16*nt
    f32x4 acc[4];
    float wsum4[4];
    #pragma unroll
    for (int nt = 0; nt < 4; ++nt) {
        const int j = m + 16 * nt;
        const float b = b_emb[j];
        acc[nt] = (f32x4){b, b, b, b};
        wsum4[nt] = W_edge[j] + W_edge[HIDC + j];
    }
    __syncthreads();

    const int node0 = blockIdx.x * 64 + wave * 16;
    const int row = min(node0 + m, N_NODESC - 1);
    const float* frow = features + (size_t)row * IN_DIMC;

    #pragma unroll
    for (int ks = 0; ks < 8; ++ks) {
        const int kk = ks * 32 + quad * 8;  // this lane's 8 k's
        const float4 fa = *(const float4*)(frow + kk);
        const float4 fb = *(const float4*)(frow + kk + 4);
        short8 af;
        af[0] = pkbf(fa.x); af[1] = pkbf(fa.y);
        af[2] = pkbf(fa.z); af[3] = pkbf(fa.w);
        af[4] = pkbf(fb.x); af[5] = pkbf(fb.y);
        af[6] = pkbf(fb.z); af[7] = pkbf(fb.w);
        #pragma unroll
        for (int nt = 0; nt < 4; ++nt) {
            const short8 bf =
                *(const short8*)&Wt[(m + 16 * nt) * WT_STRIDE + kk];
            acc[nt] = __builtin_amdgcn_mfma_f32_16x16x32_bf16(af, bf, acc[nt],
                                                              0, 0, 0);
        }
    }

    // epilogue: C/D layout col=lane&15 (=j mod 16), row=quad*4+r (=node-local)
    #pragma unroll
    for (int r = 0; r < 4; ++r) {
        float s = 0.f;
        #pragma unroll
        for (int nt = 0; nt < 4; ++nt)
            s = fmaf(fmaxf(acc[nt][r], 0.f), wsum4[nt], s);
        // reduce across the 16 lanes sharing this quad (m = bits 0..3)
        s += __shfl_xor(s, 1);
        s += __shfl_xor(s, 2);
        s += __shfl_xor(s, 4);
        s += __shfl_xor(s, 8);
        if (m == 0) {
            const int node = node0 + quad * 4 + r;
            if (node < N_NODESC) q[node] = s;
        }
    }
}

// ---------------------------------------------------------------------------
// edge kernel: gumbel-sigmoid weights + packed-u64 degree accumulation.
// One u64 atomic per endpoint: low 40 bits = fixed-point sum(wlp), bits 40+ = count.
__global__ __launch_bounds__(256) void edge_kernel(
    const int* __restrict__ edges,
    const float* __restrict__ noise,
    const float* __restrict__ b_edge,
    const float* __restrict__ q,
    unsigned long long* __restrict__ accS,
    unsigned long long* __restrict__ accD,
    float* __restrict__ out,
    const int* __restrict__ flag) {
    const int e = blockIdx.x * blockDim.x + threadIdx.x;
    if (e >= N_EDGESC) return;
    const int is64 = *flag;
    int src, dst;
    load_edge(edges, e, is64, src, dst);
    const float raw = 0.5f * (q[src] + q[dst]) + b_edge[0];
    const float u = noise[e];
    const float eps = (BIASC - (1.0f - BIASC)) * u + (1.0f - BIASC);
    const float gate = logf(eps) - log1pf(-eps);
    const float x = gate + raw;
    const float wlp = 1.0f / (1.0f + expf(-x));
    const int M2 = 2 * (N_EDGESC + N_NODESC);
    out[M2 + e] = wlp;
    out[M2 + N_EDGESC + e] = 1.0f - wlp;
    const unsigned long long t =
        (unsigned long long)(wlp * FIXSCALE + 0.5f) + CNTONE;
    atomicAdd(&accS[src], t);
    atomicAdd(&accD[dst], t);
}

// ---------------------------------------------------------------------------
// prep kernel: decode accumulators -> per-node rsqrt vector
// {r_lp_out, r_lp_in, r_hp_out, r_hp_in}
__global__ __launch_bounds__(256) void prep_kernel(
    const unsigned long long* __restrict__ accS,
    const unsigned long long* __restrict__ accD,
    float4* __restrict__ rnode) {
    const int n = blockIdx.x * blockDim.x + threadIdx.x;
    if (n >= N_NODESC) return;
    const unsigned long long a = accS[n];
    const unsigned long long b = accD[n];
    const float sumS = (float)(a & SUMMASK) * FIXINV;
    const float cntS = (float)(a >> 40);
    const float sumD = (float)(b & SUMMASK) * FIXINV;
    const float cntD = (float)(b >> 40);
    float4 r;
    r.x = rsqrtf(1.0f + sumS);          // deg_lp_out
    r.y = rsqrtf(1.0f + sumD);          // deg_lp_in
    r.z = rsqrtf(1.0f + cntS - sumS);   // deg_hp_out
    r.w = rsqrtf(1.0f + cntD - sumD);   // deg_hp_in
    rnode[n] = r;
}

// ---------------------------------------------------------------------------
// final kernel: normalized weights for edges and self-loops.
__global__ __launch_bounds__(256) void final_kernel(
    const int* __restrict__ edges,
    const float4* __restrict__ rnode,
    float* __restrict__ out,
    const int* __restrict__ flag) {
    const int i = blockIdx.x * blockDim.x + threadIdx.x;
    const int M = N_EDGESC + N_NODESC;
    if (i >= M) return;
    if (i < N_EDGESC) {
        const int is64 = *flag;
        int src, dst;
        load_edge(edges, i, is64, src, dst);
        const float wlp = out[2 * M + i] + EOSC;
        const float whp = out[2 * M + N_EDGESC + i] + EOSC;
        const float4 rs = rnode[src];
        const float4 rd = rnode[dst];
        out[i] = wlp * rs.x * rd.y;
        out[M + i] = -ALPHAC * whp * rs.z * rd.w;
    } else {
        const int n = i - N_EDGESC;
        const float4 r = rnode[n];
        out[i] = (1.0f + EOSC) * r.x * r.y;
        out[M + i] = 1.0f;
    }
}

// ---------------------------------------------------------------------------
extern "C" void kernel_launch(void* const* d_in, const int* in_sizes, int n_in,
                              void* d_out, int out_size, void* d_ws, size_t ws_size,
                              hipStream_t stream) {
    const float* features = (const float*)d_in[0];
    const int* edges      = (const int*)d_in[1];
    const float* noise    = (const float*)d_in[2];
    const float* W_emb    = (const float*)d_in[3];
    const float* b_emb    = (const float*)d_in[4];
    const float* W_edge   = (const float*)d_in[5];
    const float* b_edge   = (const float*)d_in[6];
    float* out = (float*)d_out;
    char* ws = (char*)d_ws;

    // ws layout (bytes):
    //   [0, 400000)            q        : N f32
    //   [400000, 2000000)      accS/accD: 2*N u64
    //   [2000000, 3600000)     rnode    : N float4
    //   [3600000, 3600004)     flag
    float* q = (float*)ws;
    unsigned long long* accS = (unsigned long long*)(ws + 400000);
    unsigned long long* accD = accS + N_NODESC;
    float4* rnode = (float4*)(ws + 2000000);
    int* flag = (int*)(ws + 3600000);

    hipMemsetAsync(accS, 0, 2 * N_NODESC * sizeof(unsigned long long), stream);
    node_kernel<<<(N_NODESC + 63) / 64, 256, 0, stream>>>(features, W_emb, b_emb,
                                                          W_edge, edges, q, flag);
    edge_kernel<<<(N_EDGESC + 255) / 256, 256, 0, stream>>>(edges, noise, b_edge,
                                                            q, accS, accD, out, flag);
    prep_kernel<<<(N_NODESC + 255) / 256, 256, 0, stream>>>(accS, accD, rnode);
    final_kernel<<<(N_EDGESC + N_NODESC + 255) / 256, 256, 0, stream>>>(edges, rnode,
                                                                        out, flag);
}

// Round 4
// 279.368 us; speedup vs baseline: 2.5636x; 1.2388x over previous
//
#include <hip/hip_runtime.h>
#include <hip/hip_bf16.h>
#include <math.h>

#define N_NODESC 100000
#define N_EDGESC 1600000
#define IN_DIMC 256
#define HIDC 64
#define ALPHAC 0.1f
#define BIASC 1e-4f
#define EOSC 1e-10f

#define MC (N_EDGESC + N_NODESC)   // 1,700,000
#define NBUCK 25                   // buckets of 4096 nodes
#define BCAP 68000u                // slots per bucket; 25*68000 == MC exactly
#define W20SCALE 1048576.0f        // 2^20
#define W20INV (1.0f / 1048576.0f)
#define SUMMASK ((1ull << 40) - 1)
#define CNTONE (1ull << 40)

typedef __attribute__((ext_vector_type(8))) short short8;
typedef __attribute__((ext_vector_type(4))) float f32x4;

#define WT_STRIDE 264  // bf16 per j-row: 256 + 8 pad (528 B, 16B-aligned)

// edges may arrive as int32 (JAX x64-off) or int64 little-endian.
__device__ inline void load_edge(const int* __restrict__ edges, int e, int is64,
                                 int& src, int& dst) {
    if (is64) {
        const int2 a = ((const int2*)edges)[e];
        const int2 b = ((const int2*)edges)[N_EDGESC + e];
        src = a.x; dst = b.x;
    } else {
        src = edges[e];
        dst = edges[N_EDGESC + e];
    }
}

__device__ inline short pkbf(float x) {
    union { __hip_bfloat16 b; short s; } u;
    u.b = __float2bfloat16(x);
    return u.s;
}

// ---------------------------------------------------------------------------
// node kernel (MFMA): q[n] = relu(feat[n] @ W + b) @ (We[:64]+We[64:])
// (unchanged from R3 — proven)
__global__ __launch_bounds__(256, 4) void node_kernel(
    const float* __restrict__ features,
    const float* __restrict__ W_emb,
    const float* __restrict__ b_emb,
    const float* __restrict__ W_edge,
    const int* __restrict__ edges,
    float* __restrict__ q,
    int* __restrict__ flag) {
    __shared__ __align__(16) short Wt[HIDC * WT_STRIDE];  // ~33.8 KB
    const int tid = threadIdx.x;
    if (blockIdx.x == 0 && tid == 0) {
        int z = 0;
        #pragma unroll
        for (int i = 0; i < 16; ++i) z |= edges[2 * i + 1];
        *flag = (z == 0) ? 1 : 0;  // 1 => int64 layout
    }
    {
        const float4* Wg = (const float4*)W_emb;
        #pragma unroll
        for (int i = 0; i < 16; ++i) {
            const int f4 = tid + 256 * i;
            const float4 g = Wg[f4];
            const int flat = 4 * f4;
            const int k = flat >> 6;
            const int j0 = flat & 63;
            Wt[(j0 + 0) * WT_STRIDE + k] = pkbf(g.x);
            Wt[(j0 + 1) * WT_STRIDE + k] = pkbf(g.y);
            Wt[(j0 + 2) * WT_STRIDE + k] = pkbf(g.z);
            Wt[(j0 + 3) * WT_STRIDE + k] = pkbf(g.w);
        }
    }
    const int lane = tid & 63;
    const int wave = tid >> 6;
    const int quad = lane >> 4;
    const int m = lane & 15;
    f32x4 acc[4];
    float wsum4[4];
    #pragma unroll
    for (int nt = 0; nt < 4; ++nt) {
        const int j = m + 16 * nt;
        const float b = b_emb[j];
        acc[nt] = (f32x4){b, b, b, b};
        wsum4[nt] = W_edge[j] + W_edge[HIDC + j];
    }
    __syncthreads();

    const int node0 = blockIdx.x * 64 + wave * 16;
    const int row = min(node0 + m, N_NODESC - 1);
    const float* frow = features + (size_t)row * IN_DIMC;

    #pragma unroll
    for (int ks = 0; ks < 8; ++ks) {
        const int kk = ks * 32 + quad * 8;
        const float4 fa = *(const float4*)(frow + kk);
        const float4 fb = *(const float4*)(frow + kk + 4);
        short8 af;
        af[0] = pkbf(fa.x); af[1] = pkbf(fa.y);
        af[2] = pkbf(fa.z); af[3] = pkbf(fa.w);
        af[4] = pkbf(fb.x); af[5] = pkbf(fb.y);
        af[6] = pkbf(fb.z); af[7] = pkbf(fb.w);
        #pragma unroll
        for (int nt = 0; nt < 4; ++nt) {
            const short8 bf =
                *(const short8*)&Wt[(m + 16 * nt) * WT_STRIDE + kk];
            acc[nt] = __builtin_amdgcn_mfma_f32_16x16x32_bf16(af, bf, acc[nt],
                                                              0, 0, 0);
        }
    }

    #pragma unroll
    for (int r = 0; r < 4; ++r) {
        float s = 0.f;
        #pragma unroll
        for (int nt = 0; nt < 4; ++nt)
            s = fmaf(fmaxf(acc[nt][r], 0.f), wsum4[nt], s);
        s += __shfl_xor(s, 1);
        s += __shfl_xor(s, 2);
        s += __shfl_xor(s, 4);
        s += __shfl_xor(s, 8);
        if (m == 0) {
            const int node = node0 + quad * 4 + r;
            if (node < N_NODESC) q[node] = s;
        }
    }
}

// ---------------------------------------------------------------------------
// edge_scatter: compute wlp/whp + scatter bucketed records. NO per-edge global
// atomics: LDS rank + 50 global claim atomics per block (1024 edges).
// Records: u32 = (node_local_12b << 20) | wlp_fixed_20b.
// recS lives in out[0, MC) as u32; recD in out[MC, 2*MC).
__global__ __launch_bounds__(256) void edge_scatter(
    const int* __restrict__ edges,
    const float* __restrict__ noise,
    const float* __restrict__ b_edge,
    const float* __restrict__ q,
    unsigned* __restrict__ cursorS,
    unsigned* __restrict__ cursorD,
    float* __restrict__ out,
    const int* __restrict__ flag) {
    __shared__ unsigned histS[NBUCK], histD[NBUCK];
    __shared__ unsigned baseS[NBUCK], baseD[NBUCK];
    const int tid = threadIdx.x;
    if (tid < NBUCK) { histS[tid] = 0; histD[tid] = 0; }
    __syncthreads();
    const int is64 = *flag;
    const float be = b_edge[0];
    int srcA[4], dstA[4];
    float wlpA[4];
    unsigned rkS[4], rkD[4];
    const int e0 = blockIdx.x * 1024 + tid;
    #pragma unroll
    for (int i = 0; i < 4; ++i) {
        const int e = e0 + i * 256;
        srcA[i] = -1;
        if (e < N_EDGESC) {
            int s, d;
            load_edge(edges, e, is64, s, d);
            srcA[i] = s; dstA[i] = d;
            const float raw = 0.5f * (q[s] + q[d]) + be;
            const float u = noise[e];
            const float eps = (BIASC - (1.0f - BIASC)) * u + (1.0f - BIASC);
            const float gate = logf(eps) - log1pf(-eps);
            const float wlp = 1.0f / (1.0f + expf(-(gate + raw)));
            wlpA[i] = wlp;
            out[2 * MC + e] = wlp;
            out[2 * MC + N_EDGESC + e] = 1.0f - wlp;
            rkS[i] = atomicAdd(&histS[s >> 12], 1u);
            rkD[i] = atomicAdd(&histD[d >> 12], 1u);
        }
    }
    __syncthreads();
    if (tid < NBUCK)
        baseS[tid] = atomicAdd(&cursorS[tid], histS[tid]);
    else if (tid < 2 * NBUCK)
        baseD[tid - NBUCK] = atomicAdd(&cursorD[tid - NBUCK], histD[tid - NBUCK]);
    __syncthreads();
    unsigned* recS = (unsigned*)out;
    unsigned* recD = (unsigned*)out + MC;
    #pragma unroll
    for (int i = 0; i < 4; ++i) {
        if (srcA[i] >= 0) {
            const int s = srcA[i], d = dstA[i];
            const unsigned w20 =
                min((unsigned)(wlpA[i] * W20SCALE + 0.5f), 0xFFFFFu);
            const unsigned pS = baseS[s >> 12] + rkS[i];
            const unsigned pD = baseD[d >> 12] + rkD[i];
            if (pS < BCAP)
                recS[(unsigned)(s >> 12) * BCAP + pS] =
                    ((unsigned)(s & 4095) << 20) | w20;
            if (pD < BCAP)
                recD[(unsigned)(d >> 12) * BCAP + pD] =
                    ((unsigned)(d & 4095) << 20) | w20;
        }
    }
}

// ---------------------------------------------------------------------------
// gather_kernel: one block exclusively owns one bucket (blocks 0..24 = src
// buckets, 25..49 = dst buckets). Coalesced record reads -> LDS u64 table
// (sum fixed@2^20 in low 40 bits, count at bit 40) -> plain coalesced stores.
__global__ __launch_bounds__(1024) void gather_kernel(
    const float* __restrict__ out,
    const unsigned* __restrict__ cursorS,
    const unsigned* __restrict__ cursorD,
    unsigned long long* __restrict__ accS,
    unsigned long long* __restrict__ accD) {
    __shared__ unsigned long long table[4096];
    const int bid = blockIdx.x;
    const int isD = bid >= NBUCK;
    const int bkt = isD ? bid - NBUCK : bid;
    const unsigned* rec = (const unsigned*)out + (isD ? MC : 0) +
                          (unsigned)bkt * BCAP;
    const unsigned cnt = min((isD ? cursorD : cursorS)[bkt], BCAP);
    const int tid = threadIdx.x;
    #pragma unroll
    for (int i = 0; i < 4; ++i) table[tid + 1024 * i] = 0ull;
    __syncthreads();
    for (unsigned i = tid; i < cnt; i += 1024) {
        const unsigned r = rec[i];
        atomicAdd(&table[r >> 20], CNTONE | (unsigned long long)(r & 0xFFFFFu));
    }
    __syncthreads();
    unsigned long long* acc = isD ? accD : accS;
    const int node0 = bkt << 12;
    #pragma unroll
    for (int i = 0; i < 4; ++i) {
        const int local = tid + 1024 * i;
        const int node = node0 + local;
        if (node < N_NODESC) acc[node] = table[local];
    }
}

// ---------------------------------------------------------------------------
// prep kernel: decode accumulators -> per-node rsqrt vector
__global__ __launch_bounds__(256) void prep_kernel(
    const unsigned long long* __restrict__ accS,
    const unsigned long long* __restrict__ accD,
    float4* __restrict__ rnode) {
    const int n = blockIdx.x * blockDim.x + threadIdx.x;
    if (n >= N_NODESC) return;
    const unsigned long long a = accS[n];
    const unsigned long long b = accD[n];
    const float sumS = (float)(a & SUMMASK) * W20INV;
    const float cntS = (float)(a >> 40);
    const float sumD = (float)(b & SUMMASK) * W20INV;
    const float cntD = (float)(b >> 40);
    float4 r;
    r.x = rsqrtf(1.0f + sumS);          // deg_lp_out
    r.y = rsqrtf(1.0f + sumD);          // deg_lp_in
    r.z = rsqrtf(1.0f + cntS - sumS);   // deg_hp_out
    r.w = rsqrtf(1.0f + cntD - sumD);   // deg_hp_in
    rnode[n] = r;
}

// ---------------------------------------------------------------------------
// final kernel: normalized weights for edges and self-loops.
__global__ __launch_bounds__(256) void final_kernel(
    const int* __restrict__ edges,
    const float4* __restrict__ rnode,
    float* __restrict__ out,
    const int* __restrict__ flag) {
    const int i = blockIdx.x * blockDim.x + threadIdx.x;
    if (i >= MC) return;
    if (i < N_EDGESC) {
        const int is64 = *flag;
        int src, dst;
        load_edge(edges, i, is64, src, dst);
        const float wlp = out[2 * MC + i] + EOSC;
        const float whp = out[2 * MC + N_EDGESC + i] + EOSC;
        const float4 rs = rnode[src];
        const float4 rd = rnode[dst];
        out[i] = wlp * rs.x * rd.y;
        out[MC + i] = -ALPHAC * whp * rs.z * rd.w;
    } else {
        const int n = i - N_EDGESC;
        const float4 r = rnode[n];
        out[i] = (1.0f + EOSC) * r.x * r.y;
        out[MC + i] = 1.0f;
    }
}

// ---------------------------------------------------------------------------
extern "C" void kernel_launch(void* const* d_in, const int* in_sizes, int n_in,
                              void* d_out, int out_size, void* d_ws, size_t ws_size,
                              hipStream_t stream) {
    const float* features = (const float*)d_in[0];
    const int* edges      = (const int*)d_in[1];
    const float* noise    = (const float*)d_in[2];
    const float* W_emb    = (const float*)d_in[3];
    const float* b_emb    = (const float*)d_in[4];
    const float* W_edge   = (const float*)d_in[5];
    const float* b_edge   = (const float*)d_in[6];
    float* out = (float*)d_out;
    char* ws = (char*)d_ws;

    // ws layout (bytes):
    //   [0, 400000)            q        : N f32
    //   [400000, 2000000)      accS/accD: 2*N u64
    //   [2000000, 3600000)     rnode    : N float4
    //   [3600000, 3600004)     flag
    //   [3600004, 3600204)     cursorS/cursorD : 2*25 u32
    float* q = (float*)ws;
    unsigned long long* accS = (unsigned long long*)(ws + 400000);
    unsigned long long* accD = accS + N_NODESC;
    float4* rnode = (float4*)(ws + 2000000);
    int* flag = (int*)(ws + 3600000);
    unsigned* cursorS = (unsigned*)(ws + 3600004);
    unsigned* cursorD = cursorS + NBUCK;

    hipMemsetAsync(cursorS, 0, 2 * NBUCK * sizeof(unsigned), stream);
    node_kernel<<<(N_NODESC + 63) / 64, 256, 0, stream>>>(features, W_emb, b_emb,
                                                          W_edge, edges, q, flag);
    edge_scatter<<<(N_EDGESC + 1023) / 1024, 256, 0, stream>>>(
        edges, noise, b_edge, q, cursorS, cursorD, out, flag);
    gather_kernel<<<2 * NBUCK, 1024, 0, stream>>>(out, cursorS, cursorD, accS, accD);
    prep_kernel<<<(N_NODESC + 255) / 256, 256, 0, stream>>>(accS, accD, rnode);
    final_kernel<<<(MC + 255) / 256, 256, 0, stream>>>(edges, rnode, out, flag);
}

// Round 5
// 271.093 us; speedup vs baseline: 2.6418x; 1.0305x over previous
//
#include <hip/hip_runtime.h>
#include <hip/hip_bf16.h>
#include <math.h>

#define N_NODESC 100000
#define N_EDGESC 1600000
#define IN_DIMC 256
#define HIDC 64
#define ALPHAC 0.1f
#define BIASC 1e-4f
#define EOSC 1e-10f

#define MC (N_EDGESC + N_NODESC)   // 1,700,000
#define NBUCK 50                   // buckets of 2048 nodes (shift 11)
#define BSHIFT 11
#define BMASK 2047
#define BCAP 34000u                // 2*50*34000 == 2*MC exactly
#define W20SCALE 1048576.0f        // 2^20
#define W20INV (1.0f / 1048576.0f)
#define SUMMASK ((1ull << 40) - 1)
#define CNTONE (1ull << 40)

typedef __attribute__((ext_vector_type(8))) short short8;
typedef __attribute__((ext_vector_type(4))) float f32x4;

#define WT_STRIDE 264  // bf16 per j-row: 256 + 8 pad (528 B, 16B-aligned)

// edges may arrive as int32 (JAX x64-off) or int64 little-endian.
__device__ inline void load_edge(const int* __restrict__ edges, int e, int is64,
                                 int& src, int& dst) {
    if (is64) {
        const int2 a = ((const int2*)edges)[e];
        const int2 b = ((const int2*)edges)[N_EDGESC + e];
        src = a.x; dst = b.x;
    } else {
        src = edges[e];
        dst = edges[N_EDGESC + e];
    }
}

__device__ inline short pkbf(float x) {
    union { __hip_bfloat16 b; short s; } u;
    u.b = __float2bfloat16(x);
    return u.s;
}

// ---------------------------------------------------------------------------
// node kernel (MFMA): q[n] = relu(feat[n] @ W + b) @ (We[:64]+We[64:])
// 2 node-tiles per wave (shared B-fragments, 2x ILP). Block 0 also does the
// int32/int64 detection and zeroes the 100 bucket cursors.
__global__ __launch_bounds__(256, 3) void node_kernel(
    const float* __restrict__ features,
    const float* __restrict__ W_emb,
    const float* __restrict__ b_emb,
    const float* __restrict__ W_edge,
    const int* __restrict__ edges,
    float* __restrict__ q,
    unsigned* __restrict__ cursor,
    int* __restrict__ flag) {
    __shared__ __align__(16) short Wt[HIDC * WT_STRIDE];  // ~33.8 KB
    const int tid = threadIdx.x;
    if (blockIdx.x == 0) {
        if (tid == 0) {
            int z = 0;
            #pragma unroll
            for (int i = 0; i < 16; ++i) z |= edges[2 * i + 1];
            *flag = (z == 0) ? 1 : 0;  // 1 => int64 layout
        }
        if (tid < 2 * NBUCK) cursor[tid] = 0u;
    }
    {
        const float4* Wg = (const float4*)W_emb;
        #pragma unroll
        for (int i = 0; i < 16; ++i) {
            const int f4 = tid + 256 * i;
            const float4 g = Wg[f4];
            const int flat = 4 * f4;
            const int k = flat >> 6;
            const int j0 = flat & 63;
            Wt[(j0 + 0) * WT_STRIDE + k] = pkbf(g.x);
            Wt[(j0 + 1) * WT_STRIDE + k] = pkbf(g.y);
            Wt[(j0 + 2) * WT_STRIDE + k] = pkbf(g.z);
            Wt[(j0 + 3) * WT_STRIDE + k] = pkbf(g.w);
        }
    }
    const int lane = tid & 63;
    const int wave = tid >> 6;
    const int quad = lane >> 4;
    const int m = lane & 15;
    f32x4 accA[4], accB[4];
    float wsum4[4];
    #pragma unroll
    for (int nt = 0; nt < 4; ++nt) {
        const int j = m + 16 * nt;
        const float b = b_emb[j];
        accA[nt] = (f32x4){b, b, b, b};
        accB[nt] = (f32x4){b, b, b, b};
        wsum4[nt] = W_edge[j] + W_edge[HIDC + j];
    }
    __syncthreads();

    const int node0A = blockIdx.x * 128 + wave * 16;
    const int node0B = node0A + 64;
    const float* frA = features + (size_t)min(node0A + m, N_NODESC - 1) * IN_DIMC;
    const float* frB = features + (size_t)min(node0B + m, N_NODESC - 1) * IN_DIMC;

    #pragma unroll
    for (int ks = 0; ks < 8; ++ks) {
        const int kk = ks * 32 + quad * 8;
        const float4 fa0 = *(const float4*)(frA + kk);
        const float4 fb0 = *(const float4*)(frA + kk + 4);
        const float4 fa1 = *(const float4*)(frB + kk);
        const float4 fb1 = *(const float4*)(frB + kk + 4);
        short8 afA, afB;
        afA[0] = pkbf(fa0.x); afA[1] = pkbf(fa0.y);
        afA[2] = pkbf(fa0.z); afA[3] = pkbf(fa0.w);
        afA[4] = pkbf(fb0.x); afA[5] = pkbf(fb0.y);
        afA[6] = pkbf(fb0.z); afA[7] = pkbf(fb0.w);
        afB[0] = pkbf(fa1.x); afB[1] = pkbf(fa1.y);
        afB[2] = pkbf(fa1.z); afB[3] = pkbf(fa1.w);
        afB[4] = pkbf(fb1.x); afB[5] = pkbf(fb1.y);
        afB[6] = pkbf(fb1.z); afB[7] = pkbf(fb1.w);
        #pragma unroll
        for (int nt = 0; nt < 4; ++nt) {
            const short8 bf =
                *(const short8*)&Wt[(m + 16 * nt) * WT_STRIDE + kk];
            accA[nt] = __builtin_amdgcn_mfma_f32_16x16x32_bf16(afA, bf, accA[nt],
                                                               0, 0, 0);
            accB[nt] = __builtin_amdgcn_mfma_f32_16x16x32_bf16(afB, bf, accB[nt],
                                                               0, 0, 0);
        }
    }

    #pragma unroll
    for (int r = 0; r < 4; ++r) {
        float sA = 0.f, sB = 0.f;
        #pragma unroll
        for (int nt = 0; nt < 4; ++nt) {
            sA = fmaf(fmaxf(accA[nt][r], 0.f), wsum4[nt], sA);
            sB = fmaf(fmaxf(accB[nt][r], 0.f), wsum4[nt], sB);
        }
        sA += __shfl_xor(sA, 1); sA += __shfl_xor(sA, 2);
        sA += __shfl_xor(sA, 4); sA += __shfl_xor(sA, 8);
        sB += __shfl_xor(sB, 1); sB += __shfl_xor(sB, 2);
        sB += __shfl_xor(sB, 4); sB += __shfl_xor(sB, 8);
        if (m == 0) {
            const int nA = node0A + quad * 4 + r;
            const int nB = node0B + quad * 4 + r;
            if (nA < N_NODESC) q[nA] = sA;
            if (nB < N_NODESC) q[nB] = sB;
        }
    }
}

// ---------------------------------------------------------------------------
// edge_scatter: batched loads -> batched q gathers -> compute + rank -> scatter.
// Per-wave histogram replication; one global claim per (side,bucket) per block.
// Records: u32 = (node_local_11b << 20) | wlp_fixed_20b.
// recS = out[0, MC) as u32; recD = out[MC, 2*MC).
__global__ __launch_bounds__(256) void edge_scatter(
    const int* __restrict__ edges,
    const float* __restrict__ noise,
    const float* __restrict__ b_edge,
    const float* __restrict__ q,
    unsigned* __restrict__ cursor,
    float* __restrict__ out,
    const int* __restrict__ flag) {
    __shared__ unsigned hist[2][4][NBUCK];
    __shared__ unsigned wbase[2][4][NBUCK];
    const int tid = threadIdx.x;
    const int wave = tid >> 6;
    for (int i = tid; i < 2 * 4 * NBUCK; i += 256)
        ((unsigned*)hist)[i] = 0u;
    __syncthreads();
    const int is64 = *flag;
    const float be = b_edge[0];
    const int e0 = blockIdx.x * 1024 + tid;

    int sA[4], dA[4];
    #pragma unroll
    for (int i = 0; i < 4; ++i) {
        const int e = e0 + i * 256;
        sA[i] = -1;
        if (e < N_EDGESC) load_edge(edges, e, is64, sA[i], dA[i]);
    }
    float qs[4], qd[4];
    #pragma unroll
    for (int i = 0; i < 4; ++i) {
        if (sA[i] >= 0) { qs[i] = q[sA[i]]; qd[i] = q[dA[i]]; }
    }
    float wlpA[4];
    unsigned rkS[4], rkD[4];
    #pragma unroll
    for (int i = 0; i < 4; ++i) {
        if (sA[i] >= 0) {
            const int e = e0 + i * 256;
            const float raw = 0.5f * (qs[i] + qd[i]) + be;
            const float u = noise[e];
            const float eps = (BIASC - (1.0f - BIASC)) * u + (1.0f - BIASC);
            const float gate = logf(eps) - log1pf(-eps);
            const float wlp = 1.0f / (1.0f + expf(-(gate + raw)));
            wlpA[i] = wlp;
            out[2 * MC + e] = wlp;
            out[2 * MC + N_EDGESC + e] = 1.0f - wlp;
            rkS[i] = atomicAdd(&hist[0][wave][sA[i] >> BSHIFT], 1u);
            rkD[i] = atomicAdd(&hist[1][wave][dA[i] >> BSHIFT], 1u);
        }
    }
    __syncthreads();
    // claim phase: wave 0 lanes 0..49 handle S, wave 1 lanes 0..49 handle D
    if (tid < NBUCK) {
        const unsigned h0 = hist[0][0][tid], h1 = hist[0][1][tid];
        const unsigned h2 = hist[0][2][tid], h3 = hist[0][3][tid];
        const unsigned base = atomicAdd(&cursor[tid], h0 + h1 + h2 + h3);
        wbase[0][0][tid] = base;
        wbase[0][1][tid] = base + h0;
        wbase[0][2][tid] = base + h0 + h1;
        wbase[0][3][tid] = base + h0 + h1 + h2;
    } else if (wave == 1 && (tid & 63) < NBUCK) {
        const int b = tid & 63;
        const unsigned h0 = hist[1][0][b], h1 = hist[1][1][b];
        const unsigned h2 = hist[1][2][b], h3 = hist[1][3][b];
        const unsigned base = atomicAdd(&cursor[NBUCK + b], h0 + h1 + h2 + h3);
        wbase[1][0][b] = base;
        wbase[1][1][b] = base + h0;
        wbase[1][2][b] = base + h0 + h1;
        wbase[1][3][b] = base + h0 + h1 + h2;
    }
    __syncthreads();
    unsigned* recS = (unsigned*)out;
    unsigned* recD = (unsigned*)out + MC;
    #pragma unroll
    for (int i = 0; i < 4; ++i) {
        if (sA[i] >= 0) {
            const int s = sA[i], d = dA[i];
            const unsigned w20 =
                min((unsigned)(wlpA[i] * W20SCALE + 0.5f), 0xFFFFFu);
            const unsigned pS = wbase[0][wave][s >> BSHIFT] + rkS[i];
            const unsigned pD = wbase[1][wave][d >> BSHIFT] + rkD[i];
            if (pS < BCAP)
                recS[(unsigned)(s >> BSHIFT) * BCAP + pS] =
                    ((unsigned)(s & BMASK) << 20) | w20;
            if (pD < BCAP)
                recD[(unsigned)(d >> BSHIFT) * BCAP + pD] =
                    ((unsigned)(d & BMASK) << 20) | w20;
        }
    }
}

// ---------------------------------------------------------------------------
// gather_kernel: block owns one bucket (0..49 = src side, 50..99 = dst side).
// Records -> LDS u64 table -> decode -> per-node float2 rsqrt pair.
// rS[n] = {r_lp_out, r_hp_out}; rD[n] = {r_lp_in, r_hp_in}.
__global__ __launch_bounds__(1024) void gather_kernel(
    const float* __restrict__ out,
    const unsigned* __restrict__ cursor,
    float2* __restrict__ rS,
    float2* __restrict__ rD) {
    __shared__ unsigned long long table[2048];
    const int bid = blockIdx.x;
    const int isD = bid >= NBUCK;
    const int bkt = isD ? bid - NBUCK : bid;
    const unsigned* rec = (const unsigned*)out + (isD ? MC : 0) +
                          (unsigned)bkt * BCAP;
    const unsigned cnt = min(cursor[isD ? NBUCK + bkt : bkt], BCAP);
    const int tid = threadIdx.x;
    table[tid] = 0ull;
    table[tid + 1024] = 0ull;
    __syncthreads();
    for (unsigned i = tid; i < cnt; i += 1024) {
        const unsigned r = rec[i];
        atomicAdd(&table[r >> 20], CNTONE | (unsigned long long)(r & 0xFFFFFu));
    }
    __syncthreads();
    float2* dstp = isD ? rD : rS;
    const int node0 = bkt << BSHIFT;
    #pragma unroll
    for (int j = 0; j < 2; ++j) {
        const int local = tid + 1024 * j;
        const int node = node0 + local;
        if (node < N_NODESC) {
            const unsigned long long a = table[local];
            const float sum = (float)(a & SUMMASK) * W20INV;
            const float cf = (float)(a >> 40);
            float2 r;
            r.x = rsqrtf(1.0f + sum);        // lp degree
            r.y = rsqrtf(1.0f + cf - sum);   // hp degree
            dstp[node] = r;
        }
    }
}

// ---------------------------------------------------------------------------
// final kernel: normalized weights for edges and self-loops.
__global__ __launch_bounds__(256) void final_kernel(
    const int* __restrict__ edges,
    const float2* __restrict__ rS,
    const float2* __restrict__ rD,
    float* __restrict__ out,
    const int* __restrict__ flag) {
    const int i = blockIdx.x * blockDim.x + threadIdx.x;
    if (i >= MC) return;
    if (i < N_EDGESC) {
        const int is64 = *flag;
        int src, dst;
        load_edge(edges, i, is64, src, dst);
        const float wlp = out[2 * MC + i] + EOSC;
        const float whp = out[2 * MC + N_EDGESC + i] + EOSC;
        const float2 a = rS[src];
        const float2 b = rD[dst];
        out[i] = wlp * a.x * b.x;
        out[MC + i] = -ALPHAC * whp * a.y * b.y;
    } else {
        const int n = i - N_EDGESC;
        const float2 a = rS[n];
        const float2 b = rD[n];
        out[i] = (1.0f + EOSC) * a.x * b.x;
        out[MC + i] = 1.0f;
    }
}

// ---------------------------------------------------------------------------
extern "C" void kernel_launch(void* const* d_in, const int* in_sizes, int n_in,
                              void* d_out, int out_size, void* d_ws, size_t ws_size,
                              hipStream_t stream) {
    const float* features = (const float*)d_in[0];
    const int* edges      = (const int*)d_in[1];
    const float* noise    = (const float*)d_in[2];
    const float* W_emb    = (const float*)d_in[3];
    const float* b_emb    = (const float*)d_in[4];
    const float* W_edge   = (const float*)d_in[5];
    const float* b_edge   = (const float*)d_in[6];
    float* out = (float*)d_out;
    char* ws = (char*)d_ws;

    // ws layout (bytes):
    //   [0, 400000)          q  : N f32
    //   [400000, 1200000)    rS : N float2
    //   [1200000, 2000000)   rD : N float2
    //   [3600000, 3600004)   flag
    //   [3600004, 3600404)   cursor : 2*50 u32
    float* q = (float*)ws;
    float2* rS = (float2*)(ws + 400000);
    float2* rD = (float2*)(ws + 1200000);
    int* flag = (int*)(ws + 3600000);
    unsigned* cursor = (unsigned*)(ws + 3600004);

    node_kernel<<<782, 256, 0, stream>>>(features, W_emb, b_emb, W_edge, edges,
                                         q, cursor, flag);
    edge_scatter<<<(N_EDGESC + 1023) / 1024, 256, 0, stream>>>(
        edges, noise, b_edge, q, cursor, out, flag);
    gather_kernel<<<2 * NBUCK, 1024, 0, stream>>>(out, cursor, rS, rD);
    final_kernel<<<(MC + 255) / 256, 256, 0, stream>>>(edges, rS, rD, out, flag);
}

// Round 6
// 264.714 us; speedup vs baseline: 2.7055x; 1.0241x over previous
//
#include <hip/hip_runtime.h>
#include <hip/hip_bf16.h>
#include <math.h>

#define N_NODESC 100000
#define N_EDGESC 1600000
#define IN_DIMC 256
#define HIDC 64
#define ALPHAC 0.1f
#define BIASC 1e-4f
#define EOSC 1e-10f

#define MC (N_EDGESC + N_NODESC)   // 1,700,000
#define NBUCK 100                  // buckets of 1024 nodes (shift 10)
#define BSHIFT 10
#define BMASK 1023
#define BCAP 17000u                // 2*100*17000 == 2*MC exactly
#define W20SCALE 1048576.0f        // 2^20
#define W20INV (1.0f / 1048576.0f)
#define SUMMASK ((1ull << 40) - 1)
#define CNTONE (1ull << 40)
#define EPB 8                      // edges per thread in edge_scatter

typedef __attribute__((ext_vector_type(8))) short short8;
typedef __attribute__((ext_vector_type(4))) float f32x4;

#define WT_STRIDE 264  // bf16 per j-row: 256 + 8 pad (528 B, 16B-aligned)

// edges may arrive as int32 (JAX x64-off) or int64 little-endian.
__device__ inline void load_edge(const int* __restrict__ edges, int e, int is64,
                                 int& src, int& dst) {
    if (is64) {
        const int2 a = ((const int2*)edges)[e];
        const int2 b = ((const int2*)edges)[N_EDGESC + e];
        src = a.x; dst = b.x;
    } else {
        src = edges[e];
        dst = edges[N_EDGESC + e];
    }
}

__device__ inline short pkbf(float x) {
    union { __hip_bfloat16 b; short s; } u;
    u.b = __float2bfloat16(x);
    return u.s;
}

// ---------------------------------------------------------------------------
// node kernel (MFMA): q[n] = relu(feat[n] @ W + b) @ (We[:64]+We[64:])
// 2 node-tiles per wave. Block 0 zeroes the 200 bucket cursors + detects
// int32/int64 edge layout.
__global__ __launch_bounds__(256, 3) void node_kernel(
    const float* __restrict__ features,
    const float* __restrict__ W_emb,
    const float* __restrict__ b_emb,
    const float* __restrict__ W_edge,
    const int* __restrict__ edges,
    float* __restrict__ q,
    unsigned* __restrict__ cursor,
    int* __restrict__ flag) {
    __shared__ __align__(16) short Wt[HIDC * WT_STRIDE];  // ~33.8 KB
    const int tid = threadIdx.x;
    if (blockIdx.x == 0) {
        if (tid == 0) {
            int z = 0;
            #pragma unroll
            for (int i = 0; i < 16; ++i) z |= edges[2 * i + 1];
            *flag = (z == 0) ? 1 : 0;  // 1 => int64 layout
        }
        if (tid < 2 * NBUCK) cursor[tid] = 0u;
    }
    {
        const float4* Wg = (const float4*)W_emb;
        #pragma unroll
        for (int i = 0; i < 16; ++i) {
            const int f4 = tid + 256 * i;
            const float4 g = Wg[f4];
            const int flat = 4 * f4;
            const int k = flat >> 6;
            const int j0 = flat & 63;
            Wt[(j0 + 0) * WT_STRIDE + k] = pkbf(g.x);
            Wt[(j0 + 1) * WT_STRIDE + k] = pkbf(g.y);
            Wt[(j0 + 2) * WT_STRIDE + k] = pkbf(g.z);
            Wt[(j0 + 3) * WT_STRIDE + k] = pkbf(g.w);
        }
    }
    const int lane = tid & 63;
    const int wave = tid >> 6;
    const int quad = lane >> 4;
    const int m = lane & 15;
    f32x4 accA[4], accB[4];
    float wsum4[4];
    #pragma unroll
    for (int nt = 0; nt < 4; ++nt) {
        const int j = m + 16 * nt;
        const float b = b_emb[j];
        accA[nt] = (f32x4){b, b, b, b};
        accB[nt] = (f32x4){b, b, b, b};
        wsum4[nt] = W_edge[j] + W_edge[HIDC + j];
    }
    __syncthreads();

    const int node0A = blockIdx.x * 128 + wave * 16;
    const int node0B = node0A + 64;
    const float* frA = features + (size_t)min(node0A + m, N_NODESC - 1) * IN_DIMC;
    const float* frB = features + (size_t)min(node0B + m, N_NODESC - 1) * IN_DIMC;

    #pragma unroll
    for (int ks = 0; ks < 8; ++ks) {
        const int kk = ks * 32 + quad * 8;
        const float4 fa0 = *(const float4*)(frA + kk);
        const float4 fb0 = *(const float4*)(frA + kk + 4);
        const float4 fa1 = *(const float4*)(frB + kk);
        const float4 fb1 = *(const float4*)(frB + kk + 4);
        short8 afA, afB;
        afA[0] = pkbf(fa0.x); afA[1] = pkbf(fa0.y);
        afA[2] = pkbf(fa0.z); afA[3] = pkbf(fa0.w);
        afA[4] = pkbf(fb0.x); afA[5] = pkbf(fb0.y);
        afA[6] = pkbf(fb0.z); afA[7] = pkbf(fb0.w);
        afB[0] = pkbf(fa1.x); afB[1] = pkbf(fa1.y);
        afB[2] = pkbf(fa1.z); afB[3] = pkbf(fa1.w);
        afB[4] = pkbf(fb1.x); afB[5] = pkbf(fb1.y);
        afB[6] = pkbf(fb1.z); afB[7] = pkbf(fb1.w);
        #pragma unroll
        for (int nt = 0; nt < 4; ++nt) {
            const short8 bf =
                *(const short8*)&Wt[(m + 16 * nt) * WT_STRIDE + kk];
            accA[nt] = __builtin_amdgcn_mfma_f32_16x16x32_bf16(afA, bf, accA[nt],
                                                               0, 0, 0);
            accB[nt] = __builtin_amdgcn_mfma_f32_16x16x32_bf16(afB, bf, accB[nt],
                                                               0, 0, 0);
        }
    }

    #pragma unroll
    for (int r = 0; r < 4; ++r) {
        float sA = 0.f, sB = 0.f;
        #pragma unroll
        for (int nt = 0; nt < 4; ++nt) {
            sA = fmaf(fmaxf(accA[nt][r], 0.f), wsum4[nt], sA);
            sB = fmaf(fmaxf(accB[nt][r], 0.f), wsum4[nt], sB);
        }
        sA += __shfl_xor(sA, 1); sA += __shfl_xor(sA, 2);
        sA += __shfl_xor(sA, 4); sA += __shfl_xor(sA, 8);
        sB += __shfl_xor(sB, 1); sB += __shfl_xor(sB, 2);
        sB += __shfl_xor(sB, 4); sB += __shfl_xor(sB, 8);
        if (m == 0) {
            const int nA = node0A + quad * 4 + r;
            const int nB = node0B + quad * 4 + r;
            if (nA < N_NODESC) q[nA] = sA;
            if (nB < N_NODESC) q[nB] = sB;
        }
    }
}

// ---------------------------------------------------------------------------
// edge_scatter: 8 edges/thread, fully batched phases:
// all edge loads -> all q gathers -> compute+rank -> claim -> scatter.
// Records: u32 = (node_local_10b << 20) | wlp_fixed_20b.
// recS = out[0, MC) as u32; recD = out[MC, 2*MC).
__global__ __launch_bounds__(256) void edge_scatter(
    const int* __restrict__ edges,
    const float* __restrict__ noise,
    const float* __restrict__ b_edge,
    const float* __restrict__ q,
    unsigned* __restrict__ cursor,
    float* __restrict__ out,
    const int* __restrict__ flag) {
    __shared__ unsigned hist[2][4][NBUCK];
    __shared__ unsigned wbase[2][4][NBUCK];
    const int tid = threadIdx.x;
    const int wave = tid >> 6;
    for (int i = tid; i < 2 * 4 * NBUCK; i += 256)
        ((unsigned*)hist)[i] = 0u;
    __syncthreads();
    const int is64 = *flag;
    const float be = b_edge[0];
    const int e0 = blockIdx.x * (256 * EPB) + tid;

    int sA[EPB], dA[EPB];
    #pragma unroll
    for (int i = 0; i < EPB; ++i) {
        const int e = e0 + i * 256;
        sA[i] = -1;
        if (e < N_EDGESC) load_edge(edges, e, is64, sA[i], dA[i]);
    }
    float qs[EPB], qd[EPB];
    #pragma unroll
    for (int i = 0; i < EPB; ++i) {
        if (sA[i] >= 0) { qs[i] = q[sA[i]]; qd[i] = q[dA[i]]; }
    }
    float wlpA[EPB];
    unsigned rkS[EPB], rkD[EPB];
    #pragma unroll
    for (int i = 0; i < EPB; ++i) {
        if (sA[i] >= 0) {
            const int e = e0 + i * 256;
            const float raw = 0.5f * (qs[i] + qd[i]) + be;
            const float u = noise[e];
            const float eps = (BIASC - (1.0f - BIASC)) * u + (1.0f - BIASC);
            const float gate = logf(eps) - log1pf(-eps);
            const float wlp = 1.0f / (1.0f + expf(-(gate + raw)));
            wlpA[i] = wlp;
            out[2 * MC + e] = wlp;
            out[2 * MC + N_EDGESC + e] = 1.0f - wlp;
            rkS[i] = atomicAdd(&hist[0][wave][sA[i] >> BSHIFT], 1u);
            rkD[i] = atomicAdd(&hist[1][wave][dA[i] >> BSHIFT], 1u);
        }
    }
    __syncthreads();
    // claim phase: tid<100 -> S buckets; tid in [128,228) -> D buckets
    if (tid < NBUCK) {
        const unsigned h0 = hist[0][0][tid], h1 = hist[0][1][tid];
        const unsigned h2 = hist[0][2][tid], h3 = hist[0][3][tid];
        const unsigned base = atomicAdd(&cursor[tid], h0 + h1 + h2 + h3);
        wbase[0][0][tid] = base;
        wbase[0][1][tid] = base + h0;
        wbase[0][2][tid] = base + h0 + h1;
        wbase[0][3][tid] = base + h0 + h1 + h2;
    } else if (tid >= 128 && tid < 128 + NBUCK) {
        const int b = tid - 128;
        const unsigned h0 = hist[1][0][b], h1 = hist[1][1][b];
        const unsigned h2 = hist[1][2][b], h3 = hist[1][3][b];
        const unsigned base = atomicAdd(&cursor[NBUCK + b], h0 + h1 + h2 + h3);
        wbase[1][0][b] = base;
        wbase[1][1][b] = base + h0;
        wbase[1][2][b] = base + h0 + h1;
        wbase[1][3][b] = base + h0 + h1 + h2;
    }
    __syncthreads();
    unsigned* recS = (unsigned*)out;
    unsigned* recD = (unsigned*)out + MC;
    #pragma unroll
    for (int i = 0; i < EPB; ++i) {
        if (sA[i] >= 0) {
            const int s = sA[i], d = dA[i];
            const unsigned w20 =
                min((unsigned)(wlpA[i] * W20SCALE + 0.5f), 0xFFFFFu);
            const unsigned pS = wbase[0][wave][s >> BSHIFT] + rkS[i];
            const unsigned pD = wbase[1][wave][d >> BSHIFT] + rkD[i];
            if (pS < BCAP)
                recS[(unsigned)(s >> BSHIFT) * BCAP + pS] =
                    ((unsigned)(s & BMASK) << 20) | w20;
            if (pD < BCAP)
                recD[(unsigned)(d >> BSHIFT) * BCAP + pD] =
                    ((unsigned)(d & BMASK) << 20) | w20;
        }
    }
}

// ---------------------------------------------------------------------------
// gather_kernel: block owns one bucket (0..99 = src side, 100..199 = dst).
// Records -> LDS u64 table -> decode -> per-node float2 rsqrt pair.
// rS[n] = {r_lp_out, r_hp_out}; rD[n] = {r_lp_in, r_hp_in}.
__global__ __launch_bounds__(512) void gather_kernel(
    const float* __restrict__ out,
    const unsigned* __restrict__ cursor,
    float2* __restrict__ rS,
    float2* __restrict__ rD) {
    __shared__ unsigned long long table[1024];
    const int bid = blockIdx.x;
    const int isD = bid >= NBUCK;
    const int bkt = isD ? bid - NBUCK : bid;
    const unsigned* rec = (const unsigned*)out + (isD ? MC : 0) +
                          (unsigned)bkt * BCAP;
    const unsigned cnt = min(cursor[isD ? NBUCK + bkt : bkt], BCAP);
    const int tid = threadIdx.x;
    table[tid] = 0ull;
    table[tid + 512] = 0ull;
    __syncthreads();
    for (unsigned i = tid; i < cnt; i += 512) {
        const unsigned r = rec[i];
        atomicAdd(&table[r >> 20], CNTONE | (unsigned long long)(r & 0xFFFFFu));
    }
    __syncthreads();
    float2* dstp = isD ? rD : rS;
    const int node0 = bkt << BSHIFT;
    #pragma unroll
    for (int j = 0; j < 2; ++j) {
        const int local = tid + 512 * j;
        const int node = node0 + local;
        if (node < N_NODESC) {
            const unsigned long long a = table[local];
            const float sum = (float)(a & SUMMASK) * W20INV;
            const float cf = (float)(a >> 40);
            float2 r;
            r.x = rsqrtf(1.0f + sum);        // lp degree
            r.y = rsqrtf(1.0f + cf - sum);   // hp degree
            dstp[node] = r;
        }
    }
}

// ---------------------------------------------------------------------------
// final kernel: 4 elements/thread, batched phases. Self-loop unified as an
// edge with s=d=n, wlp_eff=1+EOS (first output); second output forced 1.0.
__global__ __launch_bounds__(256) void final_kernel(
    const int* __restrict__ edges,
    const float2* __restrict__ rS,
    const float2* __restrict__ rD,
    float* __restrict__ out,
    const int* __restrict__ flag) {
    const int tid = threadIdx.x;
    const int i0 = blockIdx.x * 1024 + tid;
    const int is64 = *flag;
    int sA[4], dA[4];
    float wl[4], wh[4];
    #pragma unroll
    for (int j = 0; j < 4; ++j) {
        const int i = i0 + j * 256;
        sA[j] = -1;
        if (i < N_EDGESC) {
            load_edge(edges, i, is64, sA[j], dA[j]);
        } else if (i < MC) {
            sA[j] = dA[j] = i - N_EDGESC;
        }
    }
    #pragma unroll
    for (int j = 0; j < 4; ++j) {
        const int i = i0 + j * 256;
        if (i < N_EDGESC) {
            wl[j] = out[2 * MC + i] + EOSC;
            wh[j] = out[2 * MC + N_EDGESC + i] + EOSC;
        } else {
            wl[j] = 1.0f + EOSC;
        }
    }
    float2 a[4], b[4];
    #pragma unroll
    for (int j = 0; j < 4; ++j) {
        if (sA[j] >= 0) { a[j] = rS[sA[j]]; b[j] = rD[dA[j]]; }
    }
    #pragma unroll
    for (int j = 0; j < 4; ++j) {
        const int i = i0 + j * 256;
        if (sA[j] >= 0) {
            out[i] = wl[j] * a[j].x * b[j].x;
            out[MC + i] = (i < N_EDGESC)
                              ? -ALPHAC * wh[j] * a[j].y * b[j].y
                              : 1.0f;
        }
    }
}

// ---------------------------------------------------------------------------
extern "C" void kernel_launch(void* const* d_in, const int* in_sizes, int n_in,
                              void* d_out, int out_size, void* d_ws, size_t ws_size,
                              hipStream_t stream) {
    const float* features = (const float*)d_in[0];
    const int* edges      = (const int*)d_in[1];
    const float* noise    = (const float*)d_in[2];
    const float* W_emb    = (const float*)d_in[3];
    const float* b_emb    = (const float*)d_in[4];
    const float* W_edge   = (const float*)d_in[5];
    const float* b_edge   = (const float*)d_in[6];
    float* out = (float*)d_out;
    char* ws = (char*)d_ws;

    // ws layout (bytes):
    //   [0, 400000)          q  : N f32
    //   [400000, 1200000)    rS : N float2
    //   [1200000, 2000000)   rD : N float2
    //   [3600000, 3600004)   flag
    //   [3600004, 3600804)   cursor : 2*100 u32
    float* q = (float*)ws;
    float2* rS = (float2*)(ws + 400000);
    float2* rD = (float2*)(ws + 1200000);
    int* flag = (int*)(ws + 3600000);
    unsigned* cursor = (unsigned*)(ws + 3600004);

    node_kernel<<<782, 256, 0, stream>>>(features, W_emb, b_emb, W_edge, edges,
                                         q, cursor, flag);
    edge_scatter<<<(N_EDGESC + 256 * EPB - 1) / (256 * EPB), 256, 0, stream>>>(
        edges, noise, b_edge, q, cursor, out, flag);
    gather_kernel<<<2 * NBUCK, 512, 0, stream>>>(out, cursor, rS, rD);
    final_kernel<<<(MC + 1023) / 1024, 256, 0, stream>>>(edges, rS, rD, out, flag);
}